// Round 2
// 350.772 us; speedup vs baseline: 1.0346x; 1.0346x over previous
//
#include <hip/hip_runtime.h>
#include <hip/hip_bf16.h>

#define NN 200000
#define ND 128
#define GD 128
#define HID 512
#define NG 1024

typedef __bf16 bf16x8 __attribute__((ext_vector_type(8)));
typedef unsigned short u16x8 __attribute__((ext_vector_type(8)));
typedef float f32x16 __attribute__((ext_vector_type(16)));

// packed-weight bases in bf16 elements inside d_ws
#define PK_WI1 0u
#define PK_WI2 131072u
#define PK_WJ1 196608u
#define PK_WJ2 262144u

__device__ __forceinline__ unsigned short f2bf(float x){
  unsigned u = __builtin_bit_cast(unsigned, x);
  u += 0x7FFFu + ((u >> 16) & 1u);          // RNE
  return (unsigned short)(u >> 16);
}
__device__ __forceinline__ float bf2f(unsigned short h){
  return __builtin_bit_cast(float, ((unsigned)h) << 16);
}
__device__ __forceinline__ f32x16 mfma_bf16(u16x8 a, u16x8 b, f32x16 c){
  return __builtin_amdgcn_mfma_f32_32x32x16_bf16(
      __builtin_bit_cast(bf16x8, a), __builtin_bit_cast(bf16x8, b), c, 0, 0, 0);
}

// ---- pack fp32 weights [K][N] -> bf16 B-fragment order for 32x32x16 ----
// frag(kt,nt): lane holds B[kt*16 + (lane>>5)*8 + j][nt*32 + (lane&31)], j=0..7
// Also zeroes the output accumulator (atomics target) — replaces memset.
__global__ void pack_w(const float* __restrict__ Wi1, const float* __restrict__ Wi2,
                       const float* __restrict__ Wj1, const float* __restrict__ Wj2,
                       unsigned short* __restrict__ pk, float* __restrict__ out){
  int g = blockIdx.x * 256 + threadIdx.x;   // 40960 groups of 8 elems
  if (g < 32768) ((float4*)out)[g] = make_float4(0.f, 0.f, 0.f, 0.f); // 131072 floats
  const float* W; int N; unsigned base; int f;
  if (g < 16384)      { W = Wi1; N = 512; base = PK_WI1; f = g; }
  else if (g < 24576) { W = Wi2; N = 128; base = PK_WI2; f = g - 16384; }
  else if (g < 32768) { W = Wj1; N = 512; base = PK_WJ1; f = g - 24576; }
  else                { W = Wj2; N = 128; base = PK_WJ2; f = g - 32768; }
  int lane = f & 63;
  int t = f >> 6;
  int ntiles = N >> 5;
  int nt = t % ntiles, kt = t / ntiles;
  int k0 = kt * 16 + (lane >> 5) * 8;
  int n  = nt * 32 + (lane & 31);
  u16x8 v;
  #pragma unroll
  for (int j = 0; j < 8; ++j) v[j] = f2bf(W[(size_t)(k0 + j) * N + n]);
  *(u16x8*)(pk + base + (size_t)f * 8) = v;
}

// ---- one MLP phase: VERIFIED compute path (mfma(X,W), scalar f2bf stores) ----
// with latency-hiding scheduling only:
//  * layer-1 frags for round c+1 (or next phase, PRENEXT) prefetched into pf
//    before the barriers — bt==0 of every round consumes pf
//  * layer-2 first-half frags (b2l) issued before the barrier pair, second
//    half (b2h) right after — in flight under stores / first MFMA batch
//  * barriers: sync(readers done) -> store Ts -> sync(Ts complete); no
//    trailing barrier, so next round's layer-1 overlaps this round's layer-2
template<int NBT, bool PRENEXT>
__device__ __forceinline__ void run_phase(
    const unsigned short* __restrict__ pk,
    const float* __restrict__ b1,
    const unsigned short* Xs, unsigned short* Tsm,
    int lane, int l31, int q, int wv, int aB0, int aB1,
    unsigned w1b, unsigned w2b, unsigned nxb,
    f32x16* acc, u16x8* pf)
{
  #pragma unroll
  for (int c = 0; c < 4; ++c){
    float bb1 = b1[c * 128 + wv * 32 + l31];
    f32x16 t0, t1;
    #pragma unroll
    for (int i = 0; i < 16; ++i){ t0[i] = 0.f; t1[i] = 0.f; }

    __builtin_amdgcn_s_setprio(1);
    #pragma unroll
    for (int bt = 0; bt < NBT; ++bt){
      u16x8 bf[4];
      #pragma unroll
      for (int k = 0; k < 4; ++k){
        if (bt == 0) bf[k] = pf[k];      // prefetched before the last barriers
        else bf[k] = *(const u16x8*)(pk + w1b +
                 (unsigned)((((bt * 4 + k) * 16 + c * 4 + wv) * 64 + lane) * 8));
      }
      #pragma unroll
      for (int k = 0; k < 4; ++k){
        int ktg = bt * 4 + k;
        u16x8 a0 = *(const u16x8*)&Xs[aB0 + ktg * 16];
        u16x8 a1 = *(const u16x8*)&Xs[aB1 + ktg * 16];
        t0 = mfma_bf16(a0, bf[k], t0);   // ORIGINAL orientation: X as A, W as B
        t1 = mfma_bf16(a1, bf[k], t1);
      }
    }
    __builtin_amdgcn_s_setprio(0);

    // prefetch layer-1 frags for round c+1 (or next phase) — barrier-independent
    if (c < 3 || PRENEXT){
      unsigned nb = (c < 3) ? w1b : nxb;
      int nc = (c < 3) ? c + 1 : 0;
      #pragma unroll
      for (int k = 0; k < 4; ++k)
        pf[k] = *(const u16x8*)(pk + nb +
                 (unsigned)(((k * 16 + nc * 4 + wv) * 64 + lane) * 8));
    }
    // first half of layer-2 weight frags — issue before the barriers
    u16x8 b2l[4];
    #pragma unroll
    for (int s = 0; s < 4; ++s)
      b2l[s] = *(const u16x8*)(pk + w2b +
                 (unsigned)((((c * 8 + s) * 4 + wv) * 64 + lane) * 8));

    // bias + ReLU + bf16 pack into regs (original f2bf path), before barrier
    unsigned short us0[16], us1[16];
    #pragma unroll
    for (int reg = 0; reg < 16; ++reg){
      float v0 = t0[reg] + bb1; v0 = v0 > 0.f ? v0 : 0.f;
      float v1 = t1[reg] + bb1; v1 = v1 > 0.f ? v1 : 0.f;
      us0[reg] = f2bf(v0);
      us1[reg] = f2bf(v1);
    }

    __syncthreads();   // all waves finished READING Ts (previous round's layer-2)
    #pragma unroll
    for (int reg = 0; reg < 16; ++reg){   // original C-layout scalar stores
      int rowl = (reg & 3) + 8 * (reg >> 2) + 4 * q;
      Tsm[rowl * 136 + wv * 32 + l31]        = us0[reg];
      Tsm[(32 + rowl) * 136 + wv * 32 + l31] = us1[reg];
    }
    __syncthreads();   // Ts complete

    // second half of layer-2 frags: in flight while first half computes
    u16x8 b2h[4];
    #pragma unroll
    for (int s = 0; s < 4; ++s)
      b2h[s] = *(const u16x8*)(pk + w2b +
                 (unsigned)((((c * 8 + 4 + s) * 4 + wv) * 64 + lane) * 8));

    __builtin_amdgcn_s_setprio(1);
    #pragma unroll
    for (int mt = 0; mt < 2; ++mt)
      #pragma unroll
      for (int s = 0; s < 4; ++s){
        u16x8 a2 = *(const u16x8*)&Tsm[(mt * 32 + l31) * 136 + s * 16 + q * 8];
        acc[mt] = mfma_bf16(a2, b2l[s], acc[mt]);
      }
    #pragma unroll
    for (int mt = 0; mt < 2; ++mt)
      #pragma unroll
      for (int s = 0; s < 4; ++s){
        u16x8 a2 = *(const u16x8*)&Tsm[(mt * 32 + l31) * 136 + (4 + s) * 16 + q * 8];
        acc[mt] = mfma_bf16(a2, b2h[s], acc[mt]);
      }
    __builtin_amdgcn_s_setprio(0);
    // no trailing barrier: next round's layer-1 touches only Xs/weights;
    // the pre-store barrier above protects Ts readers.
  }
}

// ---- main fused kernel: 4 waves per block, 64 nodes per block ----
__global__ __launch_bounds__(256, 3)
void readout_main(const float* __restrict__ hT, const float* __restrict__ h0,
                  const int* __restrict__ gi,
                  const float* __restrict__ bi1, const float* __restrict__ bi2,
                  const float* __restrict__ bj1, const float* __restrict__ bj2,
                  const unsigned short* __restrict__ pk,
                  float* __restrict__ out){
  __shared__ __align__(16) unsigned short Xs[64 * 264]; // bf16 [64][256+8]
  __shared__ __align__(16) unsigned short Ts[64 * 136]; // bf16 [64][128+8]
  __shared__ int gids[64];

  const int tid  = threadIdx.x;
  const int lane = tid & 63;
  const int wv   = tid >> 6;                // 0..3
  const int l31  = lane & 31;
  const int q    = lane >> 5;
  const int m0   = blockIdx.x * 64;         // 200000 = 3125*64 exact

  // prefetch phase-i round-0 layer-1 frags; arrives under the staging loop
  u16x8 pf[4];
  #pragma unroll
  for (int k = 0; k < 4; ++k)
    pf[k] = *(const u16x8*)(pk + PK_WI1 + (unsigned)(((k * 16 + wv) * 64 + lane) * 8));

  // ---- stage X = [h_T | h_0] as bf16 (all 256 threads, 8 iters) ----
  #pragma unroll
  for (int it = 0; it < 8; ++it){
    int flat = it * 256 + tid;              // 0..2047
    int r  = flat >> 5;                     // 0..63
    int c4 = flat & 31;
    const float4 vT = ((const float4*)(hT + (size_t)(m0 + r) * ND))[c4];
    const float4 v0 = ((const float4*)(h0 + (size_t)(m0 + r) * ND))[c4];
    uint2 pT, p0;
    pT.x = f2bf(vT.x) | ((unsigned)f2bf(vT.y) << 16);
    pT.y = f2bf(vT.z) | ((unsigned)f2bf(vT.w) << 16);
    p0.x = f2bf(v0.x) | ((unsigned)f2bf(v0.y) << 16);
    p0.y = f2bf(v0.z) | ((unsigned)f2bf(v0.w) << 16);
    *(uint2*)&Xs[r * 264 + c4 * 4]       = pT;
    *(uint2*)&Xs[r * 264 + 128 + c4 * 4] = p0;
  }
  if (tid < 64){
    // dtype probe: sorted indices end at 1023 -> int32 layout; int64 high word -> 0
    bool g64 = (gi[NN - 1] == 0);
    gids[tid] = g64 ? gi[2 * (m0 + tid)] : gi[m0 + tid];
  }
  __syncthreads();

  const int aB0 = l31 * 264 + q * 8;        // A-frag row-tile 0 (nodes 0..31)
  const int aB1 = (32 + l31) * 264 + q * 8; // A-frag row-tile 1 (nodes 32..63)

  // ================= phase i: gate = sigmoid(MLP([h_T|h_0])) =================
  f32x16 gacc[2];
  #pragma unroll
  for (int i = 0; i < 16; ++i){ gacc[0][i] = 0.f; gacc[1][i] = 0.f; }
  run_phase<4, true>(pk, bi1, Xs, Ts, lane, l31, q, wv, aB0, aB1,
                     PK_WI1, PK_WI2, PK_WJ1, gacc, pf);

  // sigmoid -> packed bf16 gate registers (C-layout, col = wv*32 + l31)
  u16x8 gate[2][2];
  {
    float bb2 = bi2[wv * 32 + l31];
    #pragma unroll
    for (int mt = 0; mt < 2; ++mt)
      #pragma unroll
      for (int reg = 0; reg < 16; ++reg){
        float x = gacc[mt][reg] + bb2;
        float s = 1.f / (1.f + __expf(-x));
        gate[mt][reg >> 3][reg & 7] = f2bf(s);
      }
  }

  // ================= phase j: j = MLP(h_T) =================
  f32x16 jacc[2];
  #pragma unroll
  for (int i = 0; i < 16; ++i){ jacc[0][i] = 0.f; jacc[1][i] = 0.f; }
  run_phase<2, false>(pk, bj1, Xs, Ts, lane, l31, q, wv, aB0, aB1,
                      PK_WJ1, PK_WJ2, PK_WJ1, jacc, pf);

  // ======== epilogue: R_v = gate * (jacc + bj2); sorted-run segmented atomics ========
  // wave w owns cols [w*32, w*32+32); rows visited in ascending order.
  {
    int col = wv * 32 + l31;
    float bb = bj2[col];
    float acc = 0.f; int cg = -1;
    #pragma unroll
    for (int mt = 0; mt < 2; ++mt)
      #pragma unroll
      for (int reg = 0; reg < 16; ++reg){
        int rowl = (reg & 3) + 8 * (reg >> 2) + 4 * q;
        int row = mt * 32 + rowl;
        float g8 = bf2f(gate[mt][reg >> 3][reg & 7]);
        float rv = g8 * (jacc[mt][reg] + bb);
        int g = gids[row];
        if (g != cg){
          if (cg >= 0) atomicAdd(out + (unsigned)cg * GD + col, acc);
          acc = 0.f; cg = g;
        }
        acc += rv;
      }
    atomicAdd(out + (unsigned)cg * GD + col, acc);
  }
}

extern "C" void kernel_launch(void* const* d_in, const int* in_sizes, int n_in,
                              void* d_out, int out_size, void* d_ws, size_t ws_size,
                              hipStream_t stream){
  const float* hT  = (const float*)d_in[0];
  const float* h0  = (const float*)d_in[1];
  const int*   gi  = (const int*)d_in[2];
  const float* Wi1 = (const float*)d_in[3];
  const float* bi1 = (const float*)d_in[4];
  const float* Wi2 = (const float*)d_in[5];
  const float* bi2 = (const float*)d_in[6];
  const float* Wj1 = (const float*)d_in[7];
  const float* bj1 = (const float*)d_in[8];
  const float* Wj2 = (const float*)d_in[9];
  const float* bj2 = (const float*)d_in[10];
  float* out = (float*)d_out;
  unsigned short* pk = (unsigned short*)d_ws; // needs 655360 B

  pack_w<<<160, 256, 0, stream>>>(Wi1, Wi2, Wj1, Wj2, pk, out);
  readout_main<<<NN / 64, 256, 0, stream>>>(hT, h0, gi, bi1, bi2, bj1, bj2, pk, out);
}